// Round 15
// baseline (31.269 us; speedup 1.0000x reference)
//
#include <hip/hip_runtime.h>
#include <hip/hip_bf16.h>

#define IN_F   4096
#define OUT_F  11008
#define BATCH  32
#define NTILE  64
#define KSPLIT 8
#define GRID_N (OUT_F / NTILE)    // 172

typedef __attribute__((ext_vector_type(8))) short  bf16x8;
typedef __attribute__((ext_vector_type(4))) float  f32x4;
typedef __attribute__((ext_vector_type(4))) int    i32x4;
typedef __attribute__((ext_vector_type(4))) float  float4v;

static __device__ __constant__ float NF4_LEVELS[16] = {
    -1.0f, -0.6961928009986877f, -0.5250730514526367f, -0.39491748809814453f,
    -0.28444138169288635f, -0.18477343022823334f, -0.09105003625154495f, 0.0f,
    0.07958029955625534f, 0.16093020141124725f, 0.24611230194568634f,
    0.33791524171829224f, 0.44070982933044434f, 0.5626170039176941f,
    0.7229568362236023f, 1.0f};

// ---------------------------------------------------------------------------
// Prelude (408 blocks):
//   bid <  64: A-fragment streams in MFMA order:
//     frag[st][kb][lane] (16B) = x[st*16+(lane&15)][kb*32+(lane>>4)*8..+8) bf16
//   bid >= 64: out[b][o] = bias[o]  (base for gemm atomics)
// ---------------------------------------------------------------------------
__global__ void prelude_kernel(const float* __restrict__ x,
                               const float* __restrict__ bias,
                               unsigned short* __restrict__ frag,
                               float* __restrict__ out) {
    const int bid = blockIdx.x, tid = threadIdx.x;
    if (bid < 64) {
        int T  = bid * 256 + tid;
        int st = T >> 13;
        int kb = (T >> 6) & 127;
        int l  = T & 63;
        int row = st * 16 + (l & 15);
        int k0  = kb * 32 + (l >> 4) * 8;
        const float* src = x + (size_t)row * IN_F + k0;
        unsigned w[4];
        #pragma unroll
        for (int e = 0; e < 4; ++e) {
            unsigned lo = __builtin_bit_cast(unsigned short, __float2bfloat16(src[2 * e]));
            unsigned hi = __builtin_bit_cast(unsigned short, __float2bfloat16(src[2 * e + 1]));
            w[e] = lo | (hi << 16);
        }
        i32x4 v = { (int)w[0], (int)w[1], (int)w[2], (int)w[3] };
        *reinterpret_cast<i32x4*>(frag + ((size_t)st * 8192 + kb * 64 + l) * 8) = v;
    } else {
        int t2 = (bid - 64) * 256 + tid;     // [0, 88064)
        int i  = t2 * 4;
        int o  = i % OUT_F;
        float4v b = *reinterpret_cast<const float4v*>(bias + o);
        *reinterpret_cast<float4v*>(out + i) = b;
    }
}

// ---------------------------------------------------------------------------
// Main: grid (172, 8) = 1376 blocks, 256 thr (4 waves), 20KB LDS, 4 blk/CU.
// ZERO barriers; waves fully independent. Wave w of block (nx, by):
//   - owns out-rows rowbase = nx*64 + w*16 .. +16, k-slice [by*512, +512)
//     (= 4 scale groups), batch 0..31 -> 32 MFMA, accumulated in registers
//   - wave-private tabu (lds[w*256..]) and code buffer (lds[1024+w*1024..])
//   - scales: one float4 per lane (its row, 4 groups)
//   - epilogue: 8 coalesced atomic wave-instrs into bias-initialized out
// No cross-wave reduce, no partial buffers, no LDS aliasing.
//
// Staging: 2 rounds of 8 rows; one row-slice = 256 consecutive int32 = one
//   contiguous 1KB wave-load (lane j covers slice-k [8j,+8)); compact 4
//   int32 -> 1 code dword; store at (rl*64 + p(j)) ^ ((rl&7)<<2),
//   p(j)=(j&0x30)|((j&3)<<2)|((j>>2)&3)   [verified R13: writes 2 lanes/bank]
// Reader: ds_read_b128 at (col*64 + grp*16 + g*4) ^ ((col&7)<<2) yields
//   k-steps t=0..3 of group grp (d = grp*16 | g<<2 | t matches p(j) for
//   j = grp*16 + t*4 + g).  Same mapping as passing rounds R13/R14.
// ---------------------------------------------------------------------------
__global__ __launch_bounds__(256, 4) void nf4_gemm_kernel(
        const int* __restrict__ packed,
        const float* __restrict__ scales,
        const unsigned short* __restrict__ frag,
        float* __restrict__ out)
{
    __shared__ unsigned lds[5120];   // 4x256 tabu | 4x1024 codes (20KB)

    const int tid  = threadIdx.x;
    const int wave = tid >> 6;
    const int lane = tid & 63;
    const int col  = lane & 15;
    const int g    = lane >> 4;

    const int n0      = blockIdx.x * NTILE;
    const int by      = blockIdx.y;          // k-slice 0..7
    const int rowbase = n0 + wave * 16;

    // ---- wave-private tabu ----
    #pragma unroll
    for (int q = 0; q < 4; ++q) {
        int e = q * 64 + lane;
        unsigned lo = __builtin_bit_cast(unsigned short, __float2bfloat16(NF4_LEVELS[e & 15]));
        unsigned hi = __builtin_bit_cast(unsigned short, __float2bfloat16(NF4_LEVELS[(e >> 4) & 15]));
        lds[wave * 256 + e] = lo | (hi << 16);
    }

    // ---- scales: this lane's row, groups by*4 .. +4 ----
    float4v scv = *reinterpret_cast<const float4v*>(
        scales + (size_t)(rowbase + col) * 32 + by * 4);
    float sca[4] = { scv.x, scv.y, scv.z, scv.w };

    const int dperm = (lane & 0x30) | ((lane & 3) << 2) | ((lane >> 2) & 3);
    unsigned* cbuf = &lds[1024 + wave * 1024];

    #define SLOAD(r0, sr)                                                      \
        _Pragma("unroll")                                                      \
        for (int ii = 0; ii < 8; ++ii) {                                       \
            sr[ii] = *reinterpret_cast<const i32x4*>(                          \
                packed + (size_t)(rowbase + (r0) + ii) * (IN_F / 2)            \
                       + by * 256 + lane * 4);                                 \
        }

    #define SWRITE(r0, sr)                                                     \
        _Pragma("unroll")                                                      \
        for (int ii = 0; ii < 8; ++ii) {                                       \
            int rl = (r0) + ii;                                                \
            unsigned v = ((unsigned)(sr[ii][0] & 255))                         \
                       | ((unsigned)(sr[ii][1] & 255) << 8)                    \
                       | ((unsigned)(sr[ii][2] & 255) << 16)                   \
                       | ((unsigned)sr[ii][3] << 24);                          \
            cbuf[(rl * 64 + dperm) ^ ((rl & 7) << 2)] = v;                     \
        }

    {
        i32x4 sr[8];
        SLOAD(0, sr) SWRITE(0, sr)
        SLOAD(8, sr) SWRITE(8, sr)
    }

    f32x4 acc0 = (f32x4){0.f,0.f,0.f,0.f};   // batch 0-15
    f32x4 acc1 = (f32x4){0.f,0.f,0.f,0.f};   // batch 16-31

    const unsigned short* f0 = frag;
    const unsigned short* f1 = frag + 65536;

    #pragma unroll
    for (int grp = 0; grp < 4; ++grp) {
        // A fragments (8 x 1KB contiguous, L2-resident)
        bf16x8 A0[4], A1[4];
        #pragma unroll
        for (int t = 0; t < 4; ++t) {
            int kb = by * 16 + grp * 4 + t;
            A0[t] = *reinterpret_cast<const bf16x8*>(f0 + ((size_t)kb * 64 + lane) * 8);
            A1[t] = *reinterpret_cast<const bf16x8*>(f1 + ((size_t)kb * 64 + lane) * 8);
        }
        i32x4 cd = *reinterpret_cast<const i32x4*>(
            &cbuf[(col * 64 + grp * 16 + g * 4) ^ ((col & 7) << 2)]);

        f32x4 t0 = (f32x4){0.f,0.f,0.f,0.f};
        f32x4 t1 = (f32x4){0.f,0.f,0.f,0.f};
        #pragma unroll
        for (int t = 0; t < 4; ++t) {
            unsigned code = (unsigned)cd[t];
            i32x4 bu;                            // bfrag once, both halves
            bu[0] = (int)lds[wave * 256 + (code & 255u)];
            bu[1] = (int)lds[wave * 256 + ((code >> 8) & 255u)];
            bu[2] = (int)lds[wave * 256 + ((code >> 16) & 255u)];
            bu[3] = (int)lds[wave * 256 + (code >> 24)];
            bf16x8 bf = __builtin_bit_cast(bf16x8, bu);
            t0 = __builtin_amdgcn_mfma_f32_16x16x32_bf16(A0[t], bf, t0, 0, 0, 0);
            t1 = __builtin_amdgcn_mfma_f32_16x16x32_bf16(A1[t], bf, t1, 0, 0, 0);
        }
        #pragma unroll
        for (int j = 0; j < 4; ++j) {
            acc0[j] = fmaf(sca[grp], t0[j], acc0[j]);
            acc1[j] = fmaf(sca[grp], t1[j], acc1[j]);
        }
    }

    // ---- epilogue: direct atomics, no barrier, no reduce ----
    // D layout: batch = g*4+j (+16 for acc1), out col = rowbase + col
    // each wave-instr: 4 batch-rows x 16 consecutive cols = 64B segments
    #pragma unroll
    for (int j = 0; j < 4; ++j) {
        unsafeAtomicAdd(out + (size_t)(g * 4 + j) * OUT_F + rowbase + col, acc0[j]);
        unsafeAtomicAdd(out + (size_t)(16 + g * 4 + j) * OUT_F + rowbase + col, acc1[j]);
    }
}

// ---------------------------------------------------------------------------
extern "C" void kernel_launch(void* const* d_in, const int* in_sizes, int n_in,
                              void* d_out, int out_size, void* d_ws, size_t ws_size,
                              hipStream_t stream) {
    const float* x      = (const float*)d_in[0];
    const int*   packed = (const int*)d_in[1];
    const float* scales = (const float*)d_in[2];
    const float* bias   = (const float*)d_in[3];
    float* out = (float*)d_out;

    unsigned short* frag = (unsigned short*)d_ws;   // 256 KB

    prelude_kernel<<<408, 256, 0, stream>>>(x, bias, frag, out);
    nf4_gemm_kernel<<<dim3(GRID_N, KSPLIT), 256, 0, stream>>>(packed, scales, frag, out);
}

// Round 16
// 30.747 us; speedup vs baseline: 1.0170x; 1.0170x over previous
//
#include <hip/hip_runtime.h>
#include <hip/hip_bf16.h>

#define IN_F   4096
#define OUT_F  11008
#define BATCH  32
#define NTILE  16
#define GRID_N (OUT_F / NTILE)    // 688

typedef __attribute__((ext_vector_type(8))) short  bf16x8;
typedef __attribute__((ext_vector_type(4))) float  f32x4;
typedef __attribute__((ext_vector_type(4))) int    i32x4;
typedef __attribute__((ext_vector_type(4))) float  float4v;

static __device__ __constant__ float NF4_LEVELS[16] = {
    -1.0f, -0.6961928009986877f, -0.5250730514526367f, -0.39491748809814453f,
    -0.28444138169288635f, -0.18477343022823334f, -0.09105003625154495f, 0.0f,
    0.07958029955625534f, 0.16093020141124725f, 0.24611230194568634f,
    0.33791524171829224f, 0.44070982933044434f, 0.5626170039176941f,
    0.7229568362236023f, 1.0f};

// ---------------------------------------------------------------------------
// Prelude (64 blocks): A-fragment streams in MFMA order:
//   frag[bh][kb][lane] (16B) = x[bh*16+(lane&15)][kb*32+(lane>>4)*8..+8) bf16
// ---------------------------------------------------------------------------
__global__ void prelude_kernel(const float* __restrict__ x,
                               unsigned short* __restrict__ frag) {
    int T  = blockIdx.x * 256 + threadIdx.x;
    int st = T >> 13;
    int kb = (T >> 6) & 127;
    int l  = T & 63;
    int row = st * 16 + (l & 15);
    int k0  = kb * 32 + (l >> 4) * 8;
    const float* src = x + (size_t)row * IN_F + k0;
    unsigned w[4];
    #pragma unroll
    for (int e = 0; e < 4; ++e) {
        unsigned lo = __builtin_bit_cast(unsigned short, __float2bfloat16(src[2 * e]));
        unsigned hi = __builtin_bit_cast(unsigned short, __float2bfloat16(src[2 * e + 1]));
        w[e] = lo | (hi << 16);
    }
    i32x4 v = { (int)w[0], (int)w[1], (int)w[2], (int)w[3] };
    *reinterpret_cast<i32x4*>(frag + ((size_t)st * 8192 + kb * 64 + l) * 8) = v;
}

// ---------------------------------------------------------------------------
// Main: grid 688, 256 thr (4 waves). DEPTH-4 per-wave pipeline, barrier-free
// K-loop (R13 wave-privacy + R10 depth). Block = 16 out-rows x full K=4096.
// Wave (bh = wave>>1, kh = wave&1): 16 rows x batch-half bh x k-half kh
// (2048 k = 4 units of 512). acc = ONE f32x4. 64 MFMA/wave.
//   - wave-private tabu (1KB) + double-buffered code LDS (2 x 4KB)
//   - codes staged independently per wave (kh pair duplicates packed reads;
//     bytes proven non-binding R14/R15 — depth is the lever)
//   - ONE barrier total: batch-half pair (kh 0+1) reduce; direct store+bias.
//
// Staging per unit: 16 rows; one row-slice = 256 consecutive int32 = one
//   contiguous 1KB wave-load (lane j covers slice-k [8j,+8)); compact to code
//   dword; store at (rl*64 + p(j)) ^ ((rl&7)<<2),
//   p(j) = (j&0x30)|((j&3)<<2)|((j>>2)&3)   [verified R13/R15 mapping]
// Reader: ds_read_b128 at (col*64 + grp*16 + g*4) ^ ((col&7)<<2) yields
//   k-steps t=0..3 of group grp.
// Pipeline: SL(u+1) issued BEFORE COMPUTE(u); SW(u+1) after -> load latency
//   hides under compute; in-wave DS order guarantees correctness, no barriers.
// ---------------------------------------------------------------------------
__global__ __launch_bounds__(256, 3) void nf4_gemm_kernel(
        const int* __restrict__ packed,
        const float* __restrict__ scales,
        const float* __restrict__ bias,
        const unsigned short* __restrict__ frag,
        float* __restrict__ out)
{
    __shared__ unsigned lds[9216];   // 4x256 tabu | 4 waves x 2048 code dwords

    const int tid  = threadIdx.x;
    const int wave = tid >> 6;
    const int lane = tid & 63;
    const int col  = lane & 15;
    const int g    = lane >> 4;
    const int bh   = wave >> 1;      // batch half 0/1
    const int kh   = wave & 1;       // k half 0/1

    const int n0 = blockIdx.x * NTILE;

    // ---- wave-private tabu ----
    #pragma unroll
    for (int q = 0; q < 4; ++q) {
        int e = q * 64 + lane;
        unsigned lo = __builtin_bit_cast(unsigned short, __float2bfloat16(NF4_LEVELS[e & 15]));
        unsigned hi = __builtin_bit_cast(unsigned short, __float2bfloat16(NF4_LEVELS[(e >> 4) & 15]));
        lds[wave * 256 + e] = lo | (hi << 16);
    }

    const int dperm = (lane & 0x30) | ((lane & 3) << 2) | ((lane >> 2) & 3);
    unsigned* cbase = &lds[1024 + wave * 2048];

    // 8 row-slices of unit u (r0 = 0 or 8): contiguous 1KB wave-loads
    #define SL8(u, r0, sr)                                                     \
        _Pragma("unroll")                                                      \
        for (int ii = 0; ii < 8; ++ii) {                                       \
            sr[ii] = *reinterpret_cast<const i32x4*>(                          \
                packed + (size_t)(n0 + (r0) + ii) * (IN_F / 2)                 \
                       + kh * 1024 + (u) * 256 + lane * 4);                    \
        }

    #define SW8(u, r0, sr)                                                     \
        _Pragma("unroll")                                                      \
        for (int ii = 0; ii < 8; ++ii) {                                       \
            int rl = (r0) + ii;                                                \
            unsigned v = ((unsigned)(sr[ii][0] & 255))                         \
                       | ((unsigned)(sr[ii][1] & 255) << 8)                    \
                       | ((unsigned)(sr[ii][2] & 255) << 16)                   \
                       | ((unsigned)(sr[ii][3] & 255) << 24);                  \
            cbase[((u) & 1) * 1024 + ((rl * 64 + dperm) ^ ((rl & 7) << 2))] = v; \
        }

    f32x4 acc = (f32x4){0.f, 0.f, 0.f, 0.f};
    const unsigned short* fb = frag + bh * 65536;

    // one unit = 512 k = 4 scale groups; scv loaded per unit (L1-resident)
    #define COMPUTE(u)                                                         \
    {                                                                          \
        float4v scv = *reinterpret_cast<const float4v*>(                       \
            scales + (size_t)(n0 + col) * 32 + kh * 16 + (u) * 4);             \
        const float sca[4] = { scv.x, scv.y, scv.z, scv.w };                   \
        _Pragma("unroll")                                                      \
        for (int grp = 0; grp < 4; ++grp) {                                    \
            bf16x8 A[4];                                                       \
            _Pragma("unroll")                                                  \
            for (int t = 0; t < 4; ++t) {                                      \
                int kb = kh * 64 + (u) * 16 + grp * 4 + t;                     \
                A[t] = *reinterpret_cast<const bf16x8*>(                       \
                    fb + ((size_t)kb * 64 + lane) * 8);                        \
            }                                                                  \
            i32x4 cd = *reinterpret_cast<const i32x4*>(                        \
                &cbase[((u) & 1) * 1024 +                                      \
                       ((col * 64 + grp * 16 + g * 4) ^ ((col & 7) << 2))]);   \
            f32x4 tt = (f32x4){0.f, 0.f, 0.f, 0.f};                            \
            _Pragma("unroll")                                                  \
            for (int t = 0; t < 4; ++t) {                                      \
                unsigned code = (unsigned)cd[t];                               \
                i32x4 bu;                                                      \
                bu[0] = (int)lds[wave * 256 + (code & 255u)];                  \
                bu[1] = (int)lds[wave * 256 + ((code >> 8) & 255u)];           \
                bu[2] = (int)lds[wave * 256 + ((code >> 16) & 255u)];          \
                bu[3] = (int)lds[wave * 256 + (code >> 24)];                   \
                tt = __builtin_amdgcn_mfma_f32_16x16x32_bf16(                  \
                    A[t], __builtin_bit_cast(bf16x8, bu), tt, 0, 0, 0);        \
            }                                                                  \
            _Pragma("unroll")                                                  \
            for (int j = 0; j < 4; ++j)                                        \
                acc[j] = fmaf(sca[grp], tt[j], acc[j]);                        \
        }                                                                      \
    }

    // ---- barrier-free depth-4 pipeline ----
    i32x4 s0[8], s1[8];
    SL8(0, 0, s0) SL8(0, 8, s1) SW8(0, 0, s0) SW8(0, 8, s1)
    SL8(1, 0, s0) SL8(1, 8, s1)
    COMPUTE(0)
    SW8(1, 0, s0) SW8(1, 8, s1)
    SL8(2, 0, s0) SL8(2, 8, s1)
    COMPUTE(1)
    SW8(2, 0, s0) SW8(2, 8, s1)
    SL8(3, 0, s0) SL8(3, 8, s1)
    COMPUTE(2)
    SW8(3, 0, s0) SW8(3, 8, s1)
    COMPUTE(3)

    // ---- epilogue: kh-pair reduce via LDS (aliases own dead buf0 region) ----
    // slot = j*64 + g*16 + col  (D layout: batch row = bh*16 + g*4 + j)
    float* red = (float*)cbase;
    #pragma unroll
    for (int j = 0; j < 4; ++j)
        red[j * 64 + g * 16 + col] = acc[j];
    __syncthreads();                 // the ONE barrier

    const float* rbase = (const float*)&lds[1024];
    #pragma unroll
    for (int p = 0; p < 2; ++p) {
        int idx = p * 256 + tid;     // [0,512): b = idx>>4, c = idx&15
        int b   = idx >> 4;
        int c   = idx & 15;
        int h   = b >> 4;            // batch half
        int r   = b & 15;
        int j   = r & 3;
        int g2  = r >> 2;
        int slot = j * 64 + g2 * 16 + c;
        float s = rbase[(h * 2 + 0) * 2048 + slot]
                + rbase[(h * 2 + 1) * 2048 + slot];
        out[(size_t)b * OUT_F + n0 + c] = s + bias[n0 + c];
    }
}

// ---------------------------------------------------------------------------
extern "C" void kernel_launch(void* const* d_in, const int* in_sizes, int n_in,
                              void* d_out, int out_size, void* d_ws, size_t ws_size,
                              hipStream_t stream) {
    const float* x      = (const float*)d_in[0];
    const int*   packed = (const int*)d_in[1];
    const float* scales = (const float*)d_in[2];
    const float* bias   = (const float*)d_in[3];
    float* out = (float*)d_out;

    unsigned short* frag = (unsigned short*)d_ws;   // 256 KB

    prelude_kernel<<<64, 256, 0, stream>>>(x, frag);
    nf4_gemm_kernel<<<GRID_N, 256, 0, stream>>>(packed, scales, bias, frag, out);
}

// Round 17
// 28.489 us; speedup vs baseline: 1.0976x; 1.0792x over previous
//
#include <hip/hip_runtime.h>
#include <hip/hip_bf16.h>

#define IN_F   4096
#define OUT_F  11008
#define BATCH  32
#define NTILE  16
#define GRID_N (OUT_F / NTILE)    // 688

typedef __attribute__((ext_vector_type(8))) short  bf16x8;
typedef __attribute__((ext_vector_type(4))) float  f32x4;
typedef __attribute__((ext_vector_type(4))) int    i32x4;
typedef __attribute__((ext_vector_type(4))) float  float4v;

static __device__ __constant__ float NF4_LEVELS[16] = {
    -1.0f, -0.6961928009986877f, -0.5250730514526367f, -0.39491748809814453f,
    -0.28444138169288635f, -0.18477343022823334f, -0.09105003625154495f, 0.0f,
    0.07958029955625534f, 0.16093020141124725f, 0.24611230194568634f,
    0.33791524171829224f, 0.44070982933044434f, 0.5626170039176941f,
    0.7229568362236023f, 1.0f};

// ---------------------------------------------------------------------------
// Prelude (64 blocks): A-fragment streams in MFMA order:
//   frag[st][kb][lane] (16B) = x[st*16+(lane&15)][kb*32+(lane>>4)*8..+8) bf16
// ---------------------------------------------------------------------------
__global__ void prelude_kernel(const float* __restrict__ x,
                               unsigned short* __restrict__ frag) {
    int T  = blockIdx.x * 256 + threadIdx.x;
    int st = T >> 13;
    int kb = (T >> 6) & 127;
    int l  = T & 63;
    int row = st * 16 + (l & 15);
    int k0  = kb * 32 + (l >> 4) * 8;
    const float* src = x + (size_t)row * IN_F + k0;
    unsigned w[4];
    #pragma unroll
    for (int e = 0; e < 4; ++e) {
        unsigned lo = __builtin_bit_cast(unsigned short, __float2bfloat16(src[2 * e]));
        unsigned hi = __builtin_bit_cast(unsigned short, __float2bfloat16(src[2 * e + 1]));
        w[e] = lo | (hi << 16);
    }
    i32x4 v = { (int)w[0], (int)w[1], (int)w[2], (int)w[3] };
    *reinterpret_cast<i32x4*>(frag + ((size_t)st * 8192 + kb * 64 + l) * 8) = v;
}

// ---------------------------------------------------------------------------
// Main: grid 688, 256 thr (4 waves). R13 structure (best measured: 28.0us)
// + BANK-REPLICATED dequant table (the R16-profiled fix):
//   tab32[code*32 + (lane&31)] -> 32 copies; every lane reads its own bank
//   (addr%32 == lane%31 independent of code) => ZERO conflicts by construction.
//   R16 profile: SQ_LDS_BANK_CONFLICT=3.2M cyc (~5.3us/CU) + ~2.5x slowdown
//   on 2.7K random tabu reads/CU — the dominant identified pipe cost.
// Block = 16 out-rows x full K; wave owns k [wave*1024,+1024) = 2 units of
// 512 k; K-loop barrier-free (barriers only after table init + before reduce).
// Code buffer single-buffered (4KB/wave): SL(1) issues BEFORE COMPUTE(0)
// (loads fly under compute), SW(1) lands after — in-wave DS ordering makes
// the WAR safe without barriers.
//
// Staging (verified R13 mapping): per unit, 16 rows; one row-slice = 256
//   consecutive int32 = one contiguous 1KB wave-load (lane j covers slice-k
//   [8j,+8)); compact -> code dword; store (rl*64+p(j))^((rl&7)<<2),
//   p(j)=(j&0x30)|((j&3)<<2)|((j>>2)&3).
//   Reader: ds_read_b128 at (col*64+grp*16+g*4)^((col&7)<<2) = ksteps t0..3.
// ---------------------------------------------------------------------------
__global__ __launch_bounds__(256, 3) void nf4_gemm_kernel(
        const int* __restrict__ packed,
        const float* __restrict__ scales,
        const float* __restrict__ bias,
        const unsigned short* __restrict__ frag,
        float* __restrict__ out)
{
    __shared__ unsigned tab32[8192];   // 32KB: 256 codes x 32 bank-replicas
    __shared__ unsigned codes[4096];   // 16KB: 4 waves x 1024 dw; red alias

    const int tid  = threadIdx.x;
    const int wave = tid >> 6;
    const int lane = tid & 63;
    const int col  = lane & 15;
    const int g    = lane >> 4;
    const int lr   = lane & 31;        // private bank slot

    const int n0 = blockIdx.x * NTILE;

    // ---- replicated table init: entry i = (c=i>>5, replica i&31) ----
    #pragma unroll
    for (int q = 0; q < 32; ++q) {
        int i = q * 256 + tid;
        int c = i >> 5;
        unsigned lo = __builtin_bit_cast(unsigned short, __float2bfloat16(NF4_LEVELS[c & 15]));
        unsigned hi = __builtin_bit_cast(unsigned short, __float2bfloat16(NF4_LEVELS[(c >> 4) & 15]));
        tab32[i] = lo | (hi << 16);
    }

    // ---- scales in registers: row n0+col, groups wave*8 .. +8 ----
    float scw[8];
    {
        const float* sp = scales + (size_t)(n0 + col) * 32 + wave * 8;
        float4v sv0 = *reinterpret_cast<const float4v*>(sp);
        float4v sv1 = *reinterpret_cast<const float4v*>(sp + 4);
        scw[0]=sv0.x; scw[1]=sv0.y; scw[2]=sv0.z; scw[3]=sv0.w;
        scw[4]=sv1.x; scw[5]=sv1.y; scw[6]=sv1.z; scw[7]=sv1.w;
    }

    __syncthreads();                   // table ready (before any global loads)

    const int dperm = (lane & 0x30) | ((lane & 3) << 2) | ((lane >> 2) & 3);
    unsigned* cbuf = &codes[wave * 1024];

    #define PLOAD(u, r0, sr)                                                   \
        _Pragma("unroll")                                                      \
        for (int ii = 0; ii < 8; ++ii) {                                       \
            sr[ii] = *reinterpret_cast<const i32x4*>(                          \
                packed + (size_t)(n0 + (r0) + ii) * (IN_F / 2)                 \
                       + wave * 512 + (u) * 256 + lane * 4);                   \
        }

    #define PWRITE(r0, sr)                                                     \
        _Pragma("unroll")                                                      \
        for (int ii = 0; ii < 8; ++ii) {                                       \
            int row = (r0) + ii;                                               \
            unsigned v = ((unsigned)(sr[ii][0] & 255))                         \
                       | ((unsigned)(sr[ii][1] & 255) << 8)                    \
                       | ((unsigned)(sr[ii][2] & 255) << 16)                   \
                       | ((unsigned)(sr[ii][3] & 255) << 24);                  \
            cbuf[(row * 64 + dperm) ^ ((row & 7) << 2)] = v;                   \
        }

    f32x4 acc0 = (f32x4){0.f,0.f,0.f,0.f};   // batch 0-15
    f32x4 acc1 = (f32x4){0.f,0.f,0.f,0.f};   // batch 16-31

    const unsigned short* f0 = frag;
    const unsigned short* f1 = frag + 65536;

    // one group = 128 k: 1 b128 code read + 8 A-loads + 16 conflict-free
    // tabu reads + 8 MFMA (bfrag shared by both batch halves)
    #define COMPUTE_GRP(u, grp)                                                \
    {                                                                          \
        i32x4 cd = *reinterpret_cast<const i32x4*>(                            \
            &cbuf[(col * 64 + (grp) * 16 + g * 4) ^ ((col & 7) << 2)]);        \
        bf16x8 A0[4], A1[4];                                                   \
        _Pragma("unroll")                                                      \
        for (int t = 0; t < 4; ++t) {                                          \
            int kb = wave * 32 + (u) * 16 + (grp) * 4 + t;                     \
            A0[t] = *reinterpret_cast<const bf16x8*>(f0 + ((size_t)kb * 64 + lane) * 8); \
            A1[t] = *reinterpret_cast<const bf16x8*>(f1 + ((size_t)kb * 64 + lane) * 8); \
        }                                                                      \
        f32x4 t0 = (f32x4){0.f,0.f,0.f,0.f};                                   \
        f32x4 t1 = (f32x4){0.f,0.f,0.f,0.f};                                   \
        _Pragma("unroll")                                                      \
        for (int t = 0; t < 4; ++t) {                                          \
            unsigned code = (unsigned)cd[t];                                   \
            i32x4 bu;                                                          \
            bu[0] = (int)tab32[((code & 255u) << 5) | lr];                     \
            bu[1] = (int)tab32[(((code >> 8) & 255u) << 5) | lr];              \
            bu[2] = (int)tab32[(((code >> 16) & 255u) << 5) | lr];             \
            bu[3] = (int)tab32[((code >> 24) << 5) | lr];                      \
            bf16x8 bf = __builtin_bit_cast(bf16x8, bu);                        \
            t0 = __builtin_amdgcn_mfma_f32_16x16x32_bf16(A0[t], bf, t0, 0, 0, 0); \
            t1 = __builtin_amdgcn_mfma_f32_16x16x32_bf16(A1[t], bf, t1, 0, 0, 0); \
        }                                                                      \
        const float sc = scw[(u) * 4 + (grp)];                                 \
        _Pragma("unroll")                                                      \
        for (int j = 0; j < 4; ++j) {                                          \
            acc0[j] = fmaf(sc, t0[j], acc0[j]);                                \
            acc1[j] = fmaf(sc, t1[j], acc1[j]);                                \
        }                                                                      \
    }

    // ---- barrier-free K pipeline ----
    i32x4 sa[8], sb[8];
    PLOAD(0, 0, sa) PLOAD(0, 8, sb)
    PWRITE(0, sa)  PWRITE(8, sb)        // vmcnt drain (startup only)

    PLOAD(1, 0, sa) PLOAD(1, 8, sb)     // unit-1 loads fly under unit-0 compute

    COMPUTE_GRP(0, 0)
    COMPUTE_GRP(0, 1)
    COMPUTE_GRP(0, 2)
    COMPUTE_GRP(0, 3)

    PWRITE(0, sa)  PWRITE(8, sb)        // WAR safe: in-wave DS ordering

    COMPUTE_GRP(1, 0)
    COMPUTE_GRP(1, 1)
    COMPUTE_GRP(1, 2)
    COMPUTE_GRP(1, 3)

    // ---- epilogue: red aliases wave's own code region (reads done) ----
    float* red = (float*)cbuf;
    #pragma unroll
    for (int j = 0; j < 4; ++j) {
        red[(0 * 4 + j) * 64 + g * 16 + col] = acc0[j];
        red[(1 * 4 + j) * 64 + g * 16 + col] = acc1[j];
    }
    __syncthreads();                    // the final barrier

    const float* rbase = (const float*)codes;
    #pragma unroll
    for (int p = 0; p < 2; ++p) {
        int idx = p * 256 + tid;        // [0,512)
        int b   = idx >> 4;             // batch row
        int c   = idx & 15;             // out-feature local
        int h   = b >> 4;
        int r   = b & 15;
        int j   = r & 3;
        int g2  = r >> 2;
        int slot = (h * 4 + j) * 64 + g2 * 16 + c;
        float s = rbase[slot] + rbase[1024 + slot]
                + rbase[2048 + slot] + rbase[3072 + slot];
        out[(size_t)b * OUT_F + n0 + c] = s + bias[n0 + c];
    }
}

// ---------------------------------------------------------------------------
extern "C" void kernel_launch(void* const* d_in, const int* in_sizes, int n_in,
                              void* d_out, int out_size, void* d_ws, size_t ws_size,
                              hipStream_t stream) {
    const float* x      = (const float*)d_in[0];
    const int*   packed = (const int*)d_in[1];
    const float* scales = (const float*)d_in[2];
    const float* bias   = (const float*)d_in[3];
    float* out = (float*)d_out;

    unsigned short* frag = (unsigned short*)d_ws;   // 256 KB

    prelude_kernel<<<64, 256, 0, stream>>>(x, frag);
    nf4_gemm_kernel<<<GRID_N, 256, 0, stream>>>(packed, scales, bias, frag, out);
}